// Round 1
// baseline (2039.178 us; speedup 1.0000x reference)
//
#include <hip/hip_runtime.h>

// SeparableAttn: B=2, C=256, T=16, W=64, H=64.  All fp32.
// Cells: 0='T' (A=16,S=4096), 1='W' (A=64,S=1024), 2='H' (A=64,S=1024).
// Q/K/V are flat reinterpretations of conv buffers stored [Cout, A(,pooled), S].
// Cell 'H' un-permute: dest flat f = c*65536 + i*1024 + j*64 + a (raw reshape).
// ws usage ~160.3 MiB: qbuf(64M) kbuf(32M) vbuf(64M) Lpart attn.

constexpr int XBS = 16777216; // per-batch x floats (256*16*64*64)

// ---------------------------------------------------------------- conv1x1
// out[o, a(, p), s] = (max-pool_a?) sum_c W[o,c]*x_perm[c,a,s] + bias[o]
// Tile: 128 o x 64 n, BK=16. Thread tile 8o x 4n (x2 accs when pooling).
// X staging: CELL 0/1 offsets are contiguous runs of 64 floats -> float4
// vector loads (1 or 2 per thread per kk instead of 4/8 scalar).  CELL 2 is
// a strided 'H' gather (stride 4096) -> scalar, but pool partners are
// adjacent (off1=off0+1) -> single float2.
template<int CELL, bool POOL>
__global__ __launch_bounds__(256) void conv_kernel(
    const float* __restrict__ x, const float* __restrict__ Wm,
    const float* __restrict__ bias, float* __restrict__ out, int obs)
{
    constexpr int NS = POOL ? 32768 : 65536;   // per-out-channel stride
    constexpr int PN = POOL ? 2 : 1;

    __shared__ __align__(16) float Ws[16][132];      // [c'][o'], padded
    __shared__ __align__(16) float Xs[PN][16][64];   // [a-variant][c'][n']

    const int tid = threadIdx.x;
    const int tx = tid & 15, ty = tid >> 4;
    const int b  = blockIdx.z;
    const int o0 = blockIdx.y * 128;
    const int nt = blockIdx.x;

    int n0 = 0, a0 = 0, s0 = 0;
    if (CELL == 2) { a0 = (nt >> 8) * 16; s0 = (nt & 255) * 4; }  // 16a x 4s tile
    else           { n0 = nt * 64; }

    float acc[PN][8][4];
    #pragma unroll
    for (int pn = 0; pn < PN; ++pn)
        #pragma unroll
        for (int i = 0; i < 8; ++i)
            #pragma unroll
            for (int j = 0; j < 4; ++j) acc[pn][i][j] = 0.f;

    const float* xb = x + (size_t)b * XBS;

    for (int kk = 0; kk < 16; ++kk) {
        const int c0 = kk * 16;
        // stage W tile [128o x 16c] -> Ws[c'][o']
        #pragma unroll
        for (int r = 0; r < 8; ++r) {
            int op = r * 16 + ty;
            Ws[tx][op] = Wm[(o0 + op) * 256 + c0 + tx];
        }
        // stage X tile [16c x 64n] (x2 when pooled)
        if (CELL == 2) {
            #pragma unroll
            for (int r = 0; r < 4; ++r) {
                int e = tid + r * 256;
                int ck = e >> 6, nn = e & 63;
                const float* xc = xb + (c0 + ck) * 65536;
                int a = a0 + (nn >> 2); int s = s0 + (nn & 3);
                if (!POOL) {
                    int off0 = (s & 15) * 4096 + (s >> 4) * 64 + a;
                    Xs[0][ck][nn] = xc[off0];
                } else {
                    int off0 = (s & 15) * 4096 + (s >> 4) * 64 + 2 * a;
                    float2 t = *(const float2*)&xc[off0];
                    Xs[0][ck][nn] = t.x;
                    Xs[1][ck][nn] = t.y;
                }
            }
        } else {
            // one float4 (two when pooled) per thread: 256 thr * 4 = 16c x 64n
            const int ck = tid >> 4, nn4 = (tid & 15) * 4;
            const float* xc = xb + (c0 + ck) * 65536;
            if (!POOL) {
                int off0;
                if (CELL == 0) { off0 = n0 + nn4; }
                else {
                    int n = n0 + nn4; int a = n >> 10, sl = n & 1023;
                    off0 = (sl >> 6) * 4096 + a * 64 + (sl & 63);
                }
                *(float4*)&Xs[0][ck][nn4] = *(const float4*)&xc[off0];
            } else {
                int off0, off1;
                if (CELL == 0) {
                    int m = n0 + nn4; int p = m >> 12;
                    off0 = m + p * 4096; off1 = off0 + 4096;
                } else {
                    int m = n0 + nn4; int p = m >> 10, sl = m & 1023;
                    off0 = (sl >> 6) * 4096 + p * 128 + (sl & 63); off1 = off0 + 64;
                }
                *(float4*)&Xs[0][ck][nn4] = *(const float4*)&xc[off0];
                *(float4*)&Xs[1][ck][nn4] = *(const float4*)&xc[off1];
            }
        }
        __syncthreads();
        #pragma unroll
        for (int ck = 0; ck < 16; ++ck) {
            float w[8], xv0[4];
            *(float4*)&w[0] = *(const float4*)&Ws[ck][ty * 8];
            *(float4*)&w[4] = *(const float4*)&Ws[ck][ty * 8 + 4];
            *(float4*)&xv0[0] = *(const float4*)&Xs[0][ck][tx * 4];
            #pragma unroll
            for (int i = 0; i < 8; ++i)
                #pragma unroll
                for (int j = 0; j < 4; ++j) acc[0][i][j] += w[i] * xv0[j];
            if (POOL) {
                float xv1[4];
                *(float4*)&xv1[0] = *(const float4*)&Xs[1][ck][tx * 4];
                #pragma unroll
                for (int i = 0; i < 8; ++i)
                    #pragma unroll
                    for (int j = 0; j < 4; ++j) acc[1][i][j] += w[i] * xv1[j];
            }
        }
        __syncthreads();
    }

    float* outb = out + (size_t)b * obs;
    #pragma unroll
    for (int i = 0; i < 8; ++i) {
        int o = o0 + ty * 8 + i;
        float bv = bias[o];
        float v[4];
        #pragma unroll
        for (int j = 0; j < 4; ++j) {
            float t = acc[0][i][j];
            if (POOL) t = fmaxf(t, acc[1][i][j]);
            v[j] = t + bv;
        }
        int addr;
        if (CELL == 2) addr = o * NS + (a0 + tx) * 1024 + s0;
        else           addr = o * NS + n0 + tx * 4;
        *(float4*)&outb[addr] = make_float4(v[0], v[1], v[2], v[3]);
    }
}

// ---------------------------------------------------------------- logits
// Lpart[(b,a,p),kc] = sum_{j in chunk kc} Q[a,j]*K[j,p].  Split-K, no atomics.
template<int A, int AH, int PP, int G, int KS, int M>
__global__ __launch_bounds__(256) void logits_kernel(
    const float* __restrict__ qb, const float* __restrict__ kb,
    float* __restrict__ Lpart)
{
    const int tid = threadIdx.x;
    const int jl = tid & 63, pg = tid >> 6;
    const int p0 = pg * PP;
    const int b = blockIdx.z, a0 = blockIdx.y * G, kc = blockIdx.x;
    constexpr int CH = M / KS;
    const float* q = qb + (size_t)b * 8388608 + (size_t)a0 * M + (size_t)kc * CH;
    const float* k = kb + (size_t)b * 4194304;

    float acc[G][PP];
    #pragma unroll
    for (int g = 0; g < G; ++g)
        #pragma unroll
        for (int pp = 0; pp < PP; ++pp) acc[g][pp] = 0.f;

    for (int it = 0; it < CH / 64; ++it) {
        const int jo = jl + it * 64;            // offset within chunk
        const int j  = kc * CH + jo;            // global j
        float qv[G];
        #pragma unroll
        for (int g = 0; g < G; ++g) qv[g] = q[g * M + jo];
        float kv[PP];
        if (PP == 8) {
            float4 k0 = *(const float4*)&k[(size_t)j * AH + p0];
            float4 k1 = *(const float4*)&k[(size_t)j * AH + p0 + 4];
            kv[0]=k0.x; kv[1]=k0.y; kv[2]=k0.z; kv[3]=k0.w;
            kv[4]=k1.x; kv[5]=k1.y; kv[6]=k1.z; kv[7]=k1.w;
        } else {
            float2 k0 = *(const float2*)&k[(size_t)j * AH + p0];
            kv[0]=k0.x; if (PP > 1) kv[1]=k0.y;
        }
        #pragma unroll
        for (int g = 0; g < G; ++g)
            #pragma unroll
            for (int pp = 0; pp < PP; ++pp) acc[g][pp] += qv[g] * kv[pp];
    }

    #pragma unroll
    for (int g = 0; g < G; ++g)
        #pragma unroll
        for (int pp = 0; pp < PP; ++pp) {
            float v = acc[g][pp];
            #pragma unroll
            for (int off = 32; off; off >>= 1) v += __shfl_down(v, off, 64);
            if (jl == 0)
                Lpart[(size_t)(((b * A + a0 + g) * AH) + p0 + pp) * KS + kc] = v;
        }
}

// ---------------------------------------------------------------- softmax
__global__ __launch_bounds__(64) void softmax_kernel(
    const float* __restrict__ Lpart, float* __restrict__ attn,
    int AH, int KS)
{
    const int row = blockIdx.x;          // = b*A + a
    const int p = threadIdx.x;
    float s = 0.f;
    if (p < AH) {
        const size_t base = (size_t)(row * AH + p) * KS;
        for (int kc = 0; kc < KS; ++kc) s += Lpart[base + kc];
    }
    float m = (p < AH) ? s : -3.4e38f;
    #pragma unroll
    for (int off = 32; off; off >>= 1) m = fmaxf(m, __shfl_xor(m, off, 64));
    float e = (p < AH) ? __expf(s - m) : 0.f;
    float t = e;
    #pragma unroll
    for (int off = 32; off; off >>= 1) t += __shfl_xor(t, off, 64);
    if (p < AH) attn[(size_t)row * AH + p] = e / t;
}

// ---------------------------------------------------------------- apply
// o[b,x,a] = sum_p V[x,p]*attn[a,p];  xdst = gamma*o(un-permuted) + xsrc.
// Block per (b, c, i-chunk of IT); attnT staged ONCE per block with padded
// stride (A+1) -> conflict-free transpose writes.  Loop-invariant LDS row
// hoisted to registers each i.  In-place safe (bijective dest, same thread).
template<int CELL>
__global__ __launch_bounds__(256) void apply_kernel(
    const float* __restrict__ vbuf, const float* __restrict__ attn,
    const float* __restrict__ xsrc, float* __restrict__ xdst,
    const float* __restrict__ gp, int gidx)
{
    constexpr int A  = (CELL == 0) ? 16 : 64;
    constexpr int AH = A / 2;
    constexpr int d1 = (CELL == 0) ? 64 : (CELL == 1) ? 16 : 64;
    constexpr int d2 = (CELL == 0) ? 64 : (CELL == 1) ? 64 : 16;
    constexpr int IT = (CELL == 1) ? 4 : 8;     // i-values per block

    __shared__ float attnT[AH * (A + 1)];       // [p][a], padded
    __shared__ float vls[d2 * (AH + 1)];        // [j][p], padded

    const int tid = threadIdx.x;
    const int b = blockIdx.z, c = blockIdx.y;
    const int i0 = blockIdx.x * IT;

    // stage attnT once (padded: write addr p*(A+1)+a -> bank (p+a)&31, free)
    for (int idx = tid; idx < A * AH; idx += 256) {
        int a = idx / AH, p = idx % AH;
        attnT[p * (A + 1) + a] = attn[(size_t)b * A * AH + idx];
    }

    const float g = gp[gidx];

    for (int it = 0; it < IT; ++it) {
        const int i = i0 + it;
        __syncthreads();   // prior-iter LDS reads done (and attnT visible at it=0)
        const size_t vst = (size_t)b * 8388608 + (size_t)((c * d1 + i) * d2) * AH;
        for (int idx = tid; idx < d2 * AH; idx += 256)
            vls[(idx / AH) * (AH + 1) + (idx % AH)] = vbuf[vst + idx];
        __syncthreads();

        if (CELL < 2) {
            const int jj = tid & 63, wg = tid >> 6;   // lanes span j (coalesced)
            float vr[AH];                              // hoist vls row: stride
            #pragma unroll                             // (AH+1) -> 2/bank, free
            for (int p = 0; p < AH; ++p) vr[p] = vls[jj * (AH + 1) + p];
            #pragma unroll
            for (int r = 0; r < A / 4; ++r) {
                int a = wg + r * 4;
                float acc = 0.f;
                #pragma unroll
                for (int p = 0; p < AH; ++p) acc += vr[p] * attnT[p * (A + 1) + a];
                size_t xi = (size_t)b * XBS + c * 65536 +
                            ((CELL == 0) ? a * 4096 + i * 64 : i * 4096 + a * 64) + jj;
                xdst[xi] = g * acc + xsrc[xi];
            }
        } else {
            // 'H': dest flat = c*65536 + i*1024 + j*64 + a.  Lanes span a.
            const int al = tid & 63, jg = tid >> 6;
            float ar[AH];                              // hoist attnT row
            #pragma unroll
            for (int p = 0; p < AH; ++p) ar[p] = attnT[p * (A + 1) + al];
            #pragma unroll
            for (int r = 0; r < 4; ++r) {
                int j = jg + r * 4;
                float acc = 0.f;
                #pragma unroll
                for (int p = 0; p < AH; ++p) acc += vls[j * (AH + 1) + p] * ar[p];
                size_t xi = (size_t)b * XBS + c * 65536 + i * 1024 + j * 64 + al;
                xdst[xi] = g * acc + xsrc[xi];
            }
        }
    }
}

// ---------------------------------------------------------------- launch
extern "C" void kernel_launch(void* const* d_in, const int* in_sizes, int n_in,
                              void* d_out, int out_size, void* d_ws, size_t ws_size,
                              hipStream_t stream)
{
    const float* x  = (const float*)d_in[0];
    const float* Wq = (const float*)d_in[1];
    const float* bq = (const float*)d_in[2];
    const float* Wk = (const float*)d_in[3];
    const float* bk = (const float*)d_in[4];
    const float* Wv = (const float*)d_in[5];
    const float* bv = (const float*)d_in[6];
    const float* gm = (const float*)d_in[7];
    float* out = (float*)d_out;

    float* ws   = (float*)d_ws;
    float* qbuf = ws;                  // 16777216 f
    float* kbuf = qbuf + 16777216;     //  8388608 f
    float* vbuf = kbuf + 8388608;      // 16777216 f
    float* Lp   = vbuf + 16777216;     //    65536 f
    float* attn = Lp + 65536;          //     4096 f   (total ~160.3 MiB)

    dim3 B256(256);

    // ---- cell 0: 'T' (reads pristine x, writes d_out fully) ----
    conv_kernel<0,false><<<dim3(1024,1,2),B256,0,stream>>>(x, Wq, bq, qbuf, 8388608);
    conv_kernel<0,true ><<<dim3(512,1,2),B256,0,stream>>>(x, Wk, bk, kbuf, 4194304);
    conv_kernel<0,true ><<<dim3(512,2,2),B256,0,stream>>>(x, Wv, bv, vbuf, 8388608);
    logits_kernel<16,8,2,8,64,524288><<<dim3(64,2,2),B256,0,stream>>>(qbuf, kbuf, Lp);
    softmax_kernel<<<dim3(32),dim3(64),0,stream>>>(Lp, attn, 8, 64);
    apply_kernel<0><<<dim3(8,256,2),B256,0,stream>>>(vbuf, attn, x, out, gm, 0);

    // ---- cell 1: 'W' (in-place on d_out) ----
    conv_kernel<1,false><<<dim3(1024,1,2),B256,0,stream>>>(out, Wq+32768, bq+128, qbuf, 8388608);
    conv_kernel<1,true ><<<dim3(512,1,2),B256,0,stream>>>(out, Wk+32768, bk+128, kbuf, 4194304);
    conv_kernel<1,true ><<<dim3(512,2,2),B256,0,stream>>>(out, Wv+65536, bv+256, vbuf, 8388608);
    logits_kernel<64,32,8,8,16,131072><<<dim3(16,8,2),B256,0,stream>>>(qbuf, kbuf, Lp);
    softmax_kernel<<<dim3(128),dim3(64),0,stream>>>(Lp, attn, 32, 16);
    apply_kernel<1><<<dim3(4,256,2),B256,0,stream>>>(vbuf, attn, out, out, gm, 1);

    // ---- cell 2: 'H' (in-place on d_out) ----
    conv_kernel<2,false><<<dim3(1024,1,2),B256,0,stream>>>(out, Wq+65536, bq+256, qbuf, 8388608);
    conv_kernel<2,true ><<<dim3(512,1,2),B256,0,stream>>>(out, Wk+65536, bk+256, kbuf, 4194304);
    conv_kernel<2,true ><<<dim3(512,2,2),B256,0,stream>>>(out, Wv+131072, bv+512, vbuf, 8388608);
    logits_kernel<64,32,8,8,16,131072><<<dim3(16,8,2),B256,0,stream>>>(qbuf, kbuf, Lp);
    softmax_kernel<<<dim3(128),dim3(64),0,stream>>>(Lp, attn, 32, 16);
    apply_kernel<2><<<dim3(8,256,2),B256,0,stream>>>(vbuf, attn, out, out, gm, 2);
}

// Round 3
// 1349.475 us; speedup vs baseline: 1.5111x; 1.5111x over previous
//
#include <hip/hip_runtime.h>

// SeparableAttn: B=2, C=256, T=16, W=64, H=64.  All fp32 in/out.
// Cells: 0='T' (A=16,S=4096), 1='W' (A=64,S=1024), 2='H' (A=64,S=1024).
// Convs run on MFMA (bf16 3-term split: hi*hi + hi*lo + lo*hi ~ fp32).
//  - xsplit_kernel<CELL>: per-cell permute gather + fp32->(hi16|lo16) pack,
//    writes xTp[n][c] packed u32.  Done ONCE per cell, shared by Q/K/V.
//  - prep_w: weights pre-split to bf16 hi/lo in MFMA A-frag order (1KB/frag).
//  - mconv<POOL,LGS>: 4 waves, mfma_f32_32x32x16_bf16, waves split n
//    (no LDS read redundancy), B-tile in LDS with 16B-chunk XOR swizzle.
// Buffer layouts (qbuf/kbuf/vbuf) byte-identical to the verified kernel;
// logits/softmax/apply unchanged.
// ws: qbuf 64M + kbuf 32M + vbuf 64M + Lp/attn + wfrag 1.5M + xTp 128M ~ 304MiB.

constexpr int XBS = 16777216; // per-batch x floats (256*16*64*64)

typedef __attribute__((ext_vector_type(8)))  short short8v;   // 8 bf16 = 4 VGPR
typedef __attribute__((ext_vector_type(16))) float f32x16;    // MFMA 32x32 acc

__device__ __forceinline__ unsigned rne16(float f) {
    unsigned u = __float_as_uint(f);
    return (u + 0x7FFFu + ((u >> 16) & 1u)) >> 16;   // bf16 RNE (finite vals)
}

// ---------------------------------------------------------------- prep_w
// W[Cout][256] fp32 -> frag-ordered bf16 hi/lo.  Frag (mf,kstep,hl) = 1KB:
// lane l elem j <-> A[row = mf*32+(l&31)][k = kstep*16 + (l>>5)*8 + j].
// grid (16 kstep, Cout/32 mf, 2 hl), block 64.
__global__ __launch_bounds__(64) void prep_w(
    const float* __restrict__ W, unsigned int* __restrict__ dst)
{
    const int l = threadIdx.x;
    const int ks = blockIdx.x, mf = blockIdx.y, hl = blockIdx.z;
    const float* src = W + (mf * 32 + (l & 31)) * 256 + ks * 16 + ((l >> 5) << 3);
    unsigned pk[4];
    #pragma unroll
    for (int e = 0; e < 4; ++e) {
        float f0 = src[2 * e], f1 = src[2 * e + 1];
        unsigned b0, b1;
        if (hl == 0) {                       // hi = truncate-to-bf16
            b0 = __float_as_uint(f0) >> 16;
            b1 = __float_as_uint(f1) >> 16;
        } else {                             // lo = rne(x - hi)
            unsigned h0 = __float_as_uint(f0) & 0xFFFF0000u;
            unsigned h1 = __float_as_uint(f1) & 0xFFFF0000u;
            b0 = rne16(f0 - __uint_as_float(h0));
            b1 = rne16(f1 - __uint_as_float(h1));
        }
        pk[e] = b0 | (b1 << 16);
    }
    size_t off = ((size_t)(mf * 16 + ks) * 2 + hl) * 256 + l * 4;
    *(uint4*)&dst[off] = make_uint4(pk[0], pk[1], pk[2], pk[3]);
}

// ---------------------------------------------------------------- xsplit
// xTp[b][n][c] (packed hi16|lo16) = split(x_perm[c][n]).  Per-cell gather:
//  cell0: x-off(n)=n            n_row = nb*64+r
//  cell1: runbase=(nb&15)*4096+(nb>>4)*64 (runs over h),  n_row=nb*64+r
//  cell2: runbase=(nb&15)*4096+(nb>>4)*64 (runs over h),  n_row=r*1024+nb
// block: 64 runs x 64 c tile; LDS transpose.
template<int CELL>
__global__ __launch_bounds__(256) void xsplit_kernel(
    const float* __restrict__ src, unsigned int* __restrict__ xTp)
{
    __shared__ float T[64][66];   // [c][run], pad 66
    const int tid = threadIdx.x;
    const int b = blockIdx.z, cb = blockIdx.y, nb = blockIdx.x;
    const int runbase = (CELL == 0) ? nb * 64
                                    : ((nb & 15) * 4096 + ((nb >> 4) << 6));
    const float* sp = src + (size_t)b * XBS + (size_t)(cb * 64) * 65536 + runbase;
    #pragma unroll
    for (int i = 0; i < 4; ++i) {
        int id = tid + i * 256;
        int cl = id >> 4, rc = (id & 15) * 4;
        const float4 v = *(const float4*)&sp[(size_t)cl * 65536 + rc];
        *(float2*)&T[cl][rc]     = make_float2(v.x, v.y);
        *(float2*)&T[cl][rc + 2] = make_float2(v.z, v.w);
    }
    __syncthreads();
    unsigned int* dst = xTp + (size_t)b * (65536u * 256u);
    #pragma unroll
    for (int ps = 0; ps < 4; ++ps) {
        int r = ps * 16 + (tid >> 4);       // run index
        int c0 = (tid & 15) * 4;
        unsigned pk[4];
        #pragma unroll
        for (int e = 0; e < 4; ++e) {
            float f = T[c0 + e][r];
            unsigned hi = __float_as_uint(f) & 0xFFFF0000u;
            pk[e] = hi | rne16(f - __uint_as_float(hi));
        }
        int n_row = (CELL == 2) ? (r * 1024 + nb) : (nb * 64 + r);
        *(uint4*)&dst[(size_t)n_row * 256 + cb * 64 + c0] =
            make_uint4(pk[0], pk[1], pk[2], pk[3]);
    }
}

// ---------------------------------------------------------------- mconv
// out[o][col] = (pool-max?) sum_c W[o][c]*x_perm[c][n] + bias[o], via
// mfma_f32_32x32x16_bf16, 3-split.  Block: 128 o x (128 n | 64 m x 2 var).
// 4 waves: non-pool waves split n 4-way (all o); pool waves 2(o)x2(m).
// B-tile LDS [row][64c] bf16 hi/lo, 16B-chunk XOR swizzle (chunk ^= row&7).
// A-frags direct from global (frag-ordered, L1/L2-hot).
template<bool POOL, int LGS>
__global__ __launch_bounds__(256, 2) void mconv(
    const unsigned int* __restrict__ xTp, const unsigned int* __restrict__ wf,
    const float* __restrict__ bias, float* __restrict__ out, int obs)
{
    constexpr int NS = POOL ? 32768 : 65536;
    constexpr int MF = POOL ? 2 : 4;
    constexpr int NV = POOL ? 2 : 1;

    __shared__ __align__(16) unsigned short Bh[128 * 64];
    __shared__ __align__(16) unsigned short Bl[128 * 64];

    const int tid = threadIdx.x;
    const int lane = tid & 63, wv = tid >> 6;
    const int b = blockIdx.z, gy = blockIdx.y, nb = blockIdx.x;
    const unsigned int* xb = xTp + (size_t)b * (65536u * 256u);

    f32x16 acc[MF][NV];
    #pragma unroll
    for (int m = 0; m < MF; ++m)
        #pragma unroll
        for (int v = 0; v < NV; ++v)
            #pragma unroll
            for (int r = 0; r < 16; ++r) acc[m][v][r] = 0.f;

    for (int ko = 0; ko < 4; ++ko) {
        const int c0u = ko * 64;
        #pragma unroll
        for (int i = 0; i < 8; ++i) {
            int id = tid + i * 256;
            int row = id >> 4, q4 = id & 15;
            int n_src;
            if (!POOL) n_src = nb * 128 + row;
            else {
                int v = row >> 6, m = nb * 64 + (row & 63);
                int p = m >> LGS, s = m & ((1 << LGS) - 1);
                n_src = ((2 * p + v) << LGS) + s;
            }
            const uint4 g = *(const uint4*)&xb[(size_t)n_src * 256 + c0u + q4 * 4];
            unsigned h01 = (g.x >> 16)     | (g.y & 0xFFFF0000u);
            unsigned h23 = (g.z >> 16)     | (g.w & 0xFFFF0000u);
            unsigned l01 = (g.x & 0xFFFFu) | (g.y << 16);
            unsigned l23 = (g.z & 0xFFFFu) | (g.w << 16);
            int byt = row * 128 + (((q4 >> 1) ^ (row & 7)) << 4) + ((q4 & 1) << 3);
            *(uint2*)((char*)Bh + byt) = make_uint2(h01, h23);
            *(uint2*)((char*)Bl + byt) = make_uint2(l01, l23);
        }
        __syncthreads();
        #pragma unroll
        for (int ks = 0; ks < 4; ++ks) {
            short8v ah[MF], al[MF];
            #pragma unroll
            for (int m = 0; m < MF; ++m) {
                int mfG = gy * 4 + (POOL ? ((wv >> 1) * 2 + m) : m);
                const unsigned int* ap =
                    wf + (size_t)((mfG * 16 + ko * 4 + ks) * 2) * 256 + lane * 4;
                ah[m] = *(const short8v*)ap;
                al[m] = *(const short8v*)(ap + 256);
            }
            #pragma unroll
            for (int v = 0; v < NV; ++v) {
                int row = POOL ? (v * 64 + (wv & 1) * 32 + (lane & 31))
                               : (wv * 32 + (lane & 31));
                int byt = row * 128 + (((ks * 2 + (lane >> 5)) ^ (row & 7)) << 4);
                short8v bh = *(const short8v*)((char*)Bh + byt);
                short8v bl = *(const short8v*)((char*)Bl + byt);
                #pragma unroll
                for (int m = 0; m < MF; ++m) {
                    acc[m][v] = __builtin_amdgcn_mfma_f32_32x32x16_bf16(ah[m], bh, acc[m][v], 0, 0, 0);
                    acc[m][v] = __builtin_amdgcn_mfma_f32_32x32x16_bf16(ah[m], bl, acc[m][v], 0, 0, 0);
                    acc[m][v] = __builtin_amdgcn_mfma_f32_32x32x16_bf16(al[m], bh, acc[m][v], 0, 0, 0);
                }
            }
        }
        __syncthreads();
    }

    float* ob = out + (size_t)b * obs;
    const int colbase = POOL ? (nb * 64 + (wv & 1) * 32 + (lane & 31))
                             : (nb * 128 + wv * 32 + (lane & 31));
    #pragma unroll
    for (int m = 0; m < MF; ++m) {
        int mfG = gy * 4 + (POOL ? ((wv >> 1) * 2 + m) : m);
        #pragma unroll
        for (int r = 0; r < 16; ++r) {
            // D: col = lane&31, row = (r&3) + 8*(r>>2) + 4*(lane>>5)
            int o = mfG * 32 + (r & 3) + 8 * (r >> 2) + 4 * (lane >> 5);
            float val = POOL ? fmaxf(acc[m][0][r], acc[m][1][r]) : acc[m][0][r];
            ob[(size_t)o * NS + colbase] = val + bias[o];
        }
    }
}

// ---------------------------------------------------------------- logits
// Lpart[(b,a,p),kc] = sum_{j in chunk kc} Q[a,j]*K[j,p].  Split-K, no atomics.
template<int A, int AH, int PP, int G, int KS, int M>
__global__ __launch_bounds__(256) void logits_kernel(
    const float* __restrict__ qb, const float* __restrict__ kb,
    float* __restrict__ Lpart)
{
    const int tid = threadIdx.x;
    const int jl = tid & 63, pg = tid >> 6;
    const int p0 = pg * PP;
    const int b = blockIdx.z, a0 = blockIdx.y * G, kc = blockIdx.x;
    constexpr int CH = M / KS;
    const float* q = qb + (size_t)b * 8388608 + (size_t)a0 * M + (size_t)kc * CH;
    const float* k = kb + (size_t)b * 4194304;

    float acc[G][PP];
    #pragma unroll
    for (int g = 0; g < G; ++g)
        #pragma unroll
        for (int pp = 0; pp < PP; ++pp) acc[g][pp] = 0.f;

    for (int it = 0; it < CH / 64; ++it) {
        const int jo = jl + it * 64;
        const int j  = kc * CH + jo;
        float qv[G];
        #pragma unroll
        for (int g = 0; g < G; ++g) qv[g] = q[g * M + jo];
        float kv[PP];
        if (PP == 8) {
            float4 k0 = *(const float4*)&k[(size_t)j * AH + p0];
            float4 k1 = *(const float4*)&k[(size_t)j * AH + p0 + 4];
            kv[0]=k0.x; kv[1]=k0.y; kv[2]=k0.z; kv[3]=k0.w;
            kv[4]=k1.x; kv[5]=k1.y; kv[6]=k1.z; kv[7]=k1.w;
        } else {
            float2 k0 = *(const float2*)&k[(size_t)j * AH + p0];
            kv[0]=k0.x; if (PP > 1) kv[1]=k0.y;
        }
        #pragma unroll
        for (int g = 0; g < G; ++g)
            #pragma unroll
            for (int pp = 0; pp < PP; ++pp) acc[g][pp] += qv[g] * kv[pp];
    }

    #pragma unroll
    for (int g = 0; g < G; ++g)
        #pragma unroll
        for (int pp = 0; pp < PP; ++pp) {
            float v = acc[g][pp];
            #pragma unroll
            for (int off = 32; off; off >>= 1) v += __shfl_down(v, off, 64);
            if (jl == 0)
                Lpart[(size_t)(((b * A + a0 + g) * AH) + p0 + pp) * KS + kc] = v;
        }
}

// ---------------------------------------------------------------- softmax
__global__ __launch_bounds__(64) void softmax_kernel(
    const float* __restrict__ Lpart, float* __restrict__ attn,
    int AH, int KS)
{
    const int row = blockIdx.x;
    const int p = threadIdx.x;
    float s = 0.f;
    if (p < AH) {
        const size_t base = (size_t)(row * AH + p) * KS;
        for (int kc = 0; kc < KS; ++kc) s += Lpart[base + kc];
    }
    float m = (p < AH) ? s : -3.4e38f;
    #pragma unroll
    for (int off = 32; off; off >>= 1) m = fmaxf(m, __shfl_xor(m, off, 64));
    float e = (p < AH) ? __expf(s - m) : 0.f;
    float t = e;
    #pragma unroll
    for (int off = 32; off; off >>= 1) t += __shfl_xor(t, off, 64);
    if (p < AH) attn[(size_t)row * AH + p] = e / t;
}

// ---------------------------------------------------------------- apply
template<int CELL>
__global__ __launch_bounds__(256) void apply_kernel(
    const float* __restrict__ vbuf, const float* __restrict__ attn,
    const float* __restrict__ xsrc, float* __restrict__ xdst,
    const float* __restrict__ gp, int gidx)
{
    constexpr int A  = (CELL == 0) ? 16 : 64;
    constexpr int AH = A / 2;
    constexpr int d1 = (CELL == 0) ? 64 : (CELL == 1) ? 16 : 64;
    constexpr int d2 = (CELL == 0) ? 64 : (CELL == 1) ? 64 : 16;
    constexpr int IT = (CELL == 1) ? 4 : 8;

    __shared__ float attnT[AH * (A + 1)];
    __shared__ float vls[d2 * (AH + 1)];

    const int tid = threadIdx.x;
    const int b = blockIdx.z, c = blockIdx.y;
    const int i0 = blockIdx.x * IT;

    for (int idx = tid; idx < A * AH; idx += 256) {
        int a = idx / AH, p = idx % AH;
        attnT[p * (A + 1) + a] = attn[(size_t)b * A * AH + idx];
    }

    const float g = gp[gidx];

    for (int it = 0; it < IT; ++it) {
        const int i = i0 + it;
        __syncthreads();
        const size_t vst = (size_t)b * 8388608 + (size_t)((c * d1 + i) * d2) * AH;
        for (int idx = tid; idx < d2 * AH; idx += 256)
            vls[(idx / AH) * (AH + 1) + (idx % AH)] = vbuf[vst + idx];
        __syncthreads();

        if (CELL < 2) {
            const int jj = tid & 63, wg = tid >> 6;
            float vr[AH];
            #pragma unroll
            for (int p = 0; p < AH; ++p) vr[p] = vls[jj * (AH + 1) + p];
            #pragma unroll
            for (int r = 0; r < A / 4; ++r) {
                int a = wg + r * 4;
                float acc = 0.f;
                #pragma unroll
                for (int p = 0; p < AH; ++p) acc += vr[p] * attnT[p * (A + 1) + a];
                size_t xi = (size_t)b * XBS + c * 65536 +
                            ((CELL == 0) ? a * 4096 + i * 64 : i * 4096 + a * 64) + jj;
                xdst[xi] = g * acc + xsrc[xi];
            }
        } else {
            const int al = tid & 63, jg = tid >> 6;
            float ar[AH];
            #pragma unroll
            for (int p = 0; p < AH; ++p) ar[p] = attnT[p * (A + 1) + al];
            #pragma unroll
            for (int r = 0; r < 4; ++r) {
                int j = jg + r * 4;
                float acc = 0.f;
                #pragma unroll
                for (int p = 0; p < AH; ++p) acc += vls[j * (AH + 1) + p] * ar[p];
                size_t xi = (size_t)b * XBS + c * 65536 + i * 1024 + j * 64 + al;
                xdst[xi] = g * acc + xsrc[xi];
            }
        }
    }
}

// ---------------------------------------------------------------- launch
extern "C" void kernel_launch(void* const* d_in, const int* in_sizes, int n_in,
                              void* d_out, int out_size, void* d_ws, size_t ws_size,
                              hipStream_t stream)
{
    const float* x  = (const float*)d_in[0];
    const float* Wq = (const float*)d_in[1];
    const float* bq = (const float*)d_in[2];
    const float* Wk = (const float*)d_in[3];
    const float* bk = (const float*)d_in[4];
    const float* Wv = (const float*)d_in[5];
    const float* bv = (const float*)d_in[6];
    const float* gm = (const float*)d_in[7];
    float* out = (float*)d_out;

    float* ws   = (float*)d_ws;
    float* qbuf = ws;                      // 16777216 f
    float* kbuf = qbuf + 16777216;         //  8388608 f
    float* vbuf = kbuf + 8388608;          // 16777216 f
    float* Lp   = vbuf + 16777216;         //    65536 f
    float* attn = Lp + 65536;              //     4096 f
    unsigned int* wfb = (unsigned int*)(attn + 4096);   // 3*131072 u32 (1.5MiB)
    unsigned int* xTp = wfb + 3 * 131072;               // 33554432 u32 (128MiB)

    dim3 B256(256), B64(64);

    // weight prep (frag-ordered bf16 hi/lo) — data-independent, once up front
    for (int c = 0; c < 3; ++c) {
        unsigned int* wfc = wfb + c * 131072;
        prep_w<<<dim3(16,4,2),B64,0,stream>>>(Wq + c*32768, wfc);            // Q: 128KB
        prep_w<<<dim3(16,4,2),B64,0,stream>>>(Wk + c*32768, wfc + 32768);    // K: 128KB
        prep_w<<<dim3(16,8,2),B64,0,stream>>>(Wv + c*65536, wfc + 65536);    // V: 256KB
    }

    // ---- cell 0: 'T' ----
    xsplit_kernel<0><<<dim3(1024,4,2),B256,0,stream>>>(x, xTp);
    mconv<false,12><<<dim3(512,1,2),B256,0,stream>>>(xTp, wfb,          bq, qbuf, 8388608);
    mconv<true ,12><<<dim3(512,1,2),B256,0,stream>>>(xTp, wfb + 32768,  bk, kbuf, 4194304);
    mconv<true ,12><<<dim3(512,2,2),B256,0,stream>>>(xTp, wfb + 65536,  bv, vbuf, 8388608);
    logits_kernel<16,8,2,8,64,524288><<<dim3(64,2,2),B256,0,stream>>>(qbuf, kbuf, Lp);
    softmax_kernel<<<dim3(32),B64,0,stream>>>(Lp, attn, 8, 64);
    apply_kernel<0><<<dim3(8,256,2),B256,0,stream>>>(vbuf, attn, x, out, gm, 0);

    // ---- cell 1: 'W' ----
    unsigned int* wf1 = wfb + 131072;
    xsplit_kernel<1><<<dim3(1024,4,2),B256,0,stream>>>(out, xTp);
    mconv<false,10><<<dim3(512,1,2),B256,0,stream>>>(xTp, wf1,          bq+128, qbuf, 8388608);
    mconv<true ,10><<<dim3(512,1,2),B256,0,stream>>>(xTp, wf1 + 32768,  bk+128, kbuf, 4194304);
    mconv<true ,10><<<dim3(512,2,2),B256,0,stream>>>(xTp, wf1 + 65536,  bv+256, vbuf, 8388608);
    logits_kernel<64,32,8,8,16,131072><<<dim3(16,8,2),B256,0,stream>>>(qbuf, kbuf, Lp);
    softmax_kernel<<<dim3(128),B64,0,stream>>>(Lp, attn, 32, 16);
    apply_kernel<1><<<dim3(4,256,2),B256,0,stream>>>(vbuf, attn, out, out, gm, 1);

    // ---- cell 2: 'H' ----
    unsigned int* wf2 = wfb + 262144;
    xsplit_kernel<2><<<dim3(1024,4,2),B256,0,stream>>>(out, xTp);
    mconv<false,10><<<dim3(512,1,2),B256,0,stream>>>(xTp, wf2,          bq+256, qbuf, 8388608);
    mconv<true ,10><<<dim3(512,1,2),B256,0,stream>>>(xTp, wf2 + 32768,  bk+256, kbuf, 4194304);
    mconv<true ,10><<<dim3(512,2,2),B256,0,stream>>>(xTp, wf2 + 65536,  bv+512, vbuf, 8388608);
    logits_kernel<64,32,8,8,16,131072><<<dim3(16,8,2),B256,0,stream>>>(qbuf, kbuf, Lp);
    softmax_kernel<<<dim3(128),B64,0,stream>>>(Lp, attn, 32, 16);
    apply_kernel<2><<<dim3(8,256,2),B256,0,stream>>>(vbuf, attn, out, out, gm, 2);
}

// Round 4
// 1267.759 us; speedup vs baseline: 1.6085x; 1.0645x over previous
//
#include <hip/hip_runtime.h>

// SeparableAttn: B=2, C=256, T=16, W=64, H=64.  All fp32 in/out.
// Cells: 0='T' (A=16,S=4096), 1='W' (A=64,S=1024), 2='H' (A=64,S=1024).
// Convs run on MFMA (bf16 3-term split).  Applies register-tiled 4x4 fp32.
// ws: qbuf 64M + kbuf 32M + vbuf 64M + Lp/attn + wfrag 1.5M + xTp 128M ~ 304MiB.

constexpr int XBS = 16777216; // per-batch x floats (256*16*64*64)

typedef __attribute__((ext_vector_type(8)))  short short8v;   // 8 bf16 = 4 VGPR
typedef __attribute__((ext_vector_type(16))) float f32x16;    // MFMA 32x32 acc

__device__ __forceinline__ unsigned rne16(float f) {
    unsigned u = __float_as_uint(f);
    return (u + 0x7FFFu + ((u >> 16) & 1u)) >> 16;   // bf16 RNE (finite vals)
}

// ---------------------------------------------------------------- prep_w
// W[Cout][256] fp32 -> frag-ordered bf16 hi/lo.  Frag (mf,kstep,hl) = 1KB:
// lane l elem j <-> A[row = mf*32+(l&31)][k = kstep*16 + (l>>5)*8 + j].
__global__ __launch_bounds__(64) void prep_w(
    const float* __restrict__ W, unsigned int* __restrict__ dst)
{
    const int l = threadIdx.x;
    const int ks = blockIdx.x, mf = blockIdx.y, hl = blockIdx.z;
    const float* src = W + (mf * 32 + (l & 31)) * 256 + ks * 16 + ((l >> 5) << 3);
    unsigned pk[4];
    #pragma unroll
    for (int e = 0; e < 4; ++e) {
        float f0 = src[2 * e], f1 = src[2 * e + 1];
        unsigned b0, b1;
        if (hl == 0) {
            b0 = __float_as_uint(f0) >> 16;
            b1 = __float_as_uint(f1) >> 16;
        } else {
            unsigned h0 = __float_as_uint(f0) & 0xFFFF0000u;
            unsigned h1 = __float_as_uint(f1) & 0xFFFF0000u;
            b0 = rne16(f0 - __uint_as_float(h0));
            b1 = rne16(f1 - __uint_as_float(h1));
        }
        pk[e] = b0 | (b1 << 16);
    }
    size_t off = ((size_t)(mf * 16 + ks) * 2 + hl) * 256 + l * 4;
    *(uint4*)&dst[off] = make_uint4(pk[0], pk[1], pk[2], pk[3]);
}

// ---------------------------------------------------------------- xsplit
// xTp[b][n][c] (packed hi16|lo16) = split(x_perm[c][n]).
template<int CELL>
__global__ __launch_bounds__(256) void xsplit_kernel(
    const float* __restrict__ src, unsigned int* __restrict__ xTp)
{
    __shared__ float T[64][66];   // [c][run], pad 66
    const int tid = threadIdx.x;
    const int b = blockIdx.z, cb = blockIdx.y, nb = blockIdx.x;
    const int runbase = (CELL == 0) ? nb * 64
                                    : ((nb & 15) * 4096 + ((nb >> 4) << 6));
    const float* sp = src + (size_t)b * XBS + (size_t)(cb * 64) * 65536 + runbase;
    #pragma unroll
    for (int i = 0; i < 4; ++i) {
        int id = tid + i * 256;
        int cl = id >> 4, rc = (id & 15) * 4;
        const float4 v = *(const float4*)&sp[(size_t)cl * 65536 + rc];
        *(float2*)&T[cl][rc]     = make_float2(v.x, v.y);
        *(float2*)&T[cl][rc + 2] = make_float2(v.z, v.w);
    }
    __syncthreads();
    unsigned int* dst = xTp + (size_t)b * (65536u * 256u);
    #pragma unroll
    for (int ps = 0; ps < 4; ++ps) {
        int r = ps * 16 + (tid >> 4);       // run index
        int c0 = (tid & 15) * 4;
        unsigned pk[4];
        #pragma unroll
        for (int e = 0; e < 4; ++e) {
            float f = T[c0 + e][r];
            unsigned hi = __float_as_uint(f) & 0xFFFF0000u;
            pk[e] = hi | rne16(f - __uint_as_float(hi));
        }
        int n_row = (CELL == 2) ? (r * 1024 + nb) : (nb * 64 + r);
        *(uint4*)&dst[(size_t)n_row * 256 + cb * 64 + c0] =
            make_uint4(pk[0], pk[1], pk[2], pk[3]);
    }
}

// ---------------------------------------------------------------- mconv
// out[o][col] = (pool-max?) sum_c W[o][c]*x_perm[c][n] + bias[o], via
// mfma_f32_32x32x16_bf16, 3-split.  (unchanged, verified)
template<bool POOL, int LGS>
__global__ __launch_bounds__(256, 2) void mconv(
    const unsigned int* __restrict__ xTp, const unsigned int* __restrict__ wf,
    const float* __restrict__ bias, float* __restrict__ out, int obs)
{
    constexpr int NS = POOL ? 32768 : 65536;
    constexpr int MF = POOL ? 2 : 4;
    constexpr int NV = POOL ? 2 : 1;

    __shared__ __align__(16) unsigned short Bh[128 * 64];
    __shared__ __align__(16) unsigned short Bl[128 * 64];

    const int tid = threadIdx.x;
    const int lane = tid & 63, wv = tid >> 6;
    const int b = blockIdx.z, gy = blockIdx.y, nb = blockIdx.x;
    const unsigned int* xb = xTp + (size_t)b * (65536u * 256u);

    f32x16 acc[MF][NV];
    #pragma unroll
    for (int m = 0; m < MF; ++m)
        #pragma unroll
        for (int v = 0; v < NV; ++v)
            #pragma unroll
            for (int r = 0; r < 16; ++r) acc[m][v][r] = 0.f;

    for (int ko = 0; ko < 4; ++ko) {
        const int c0u = ko * 64;
        #pragma unroll
        for (int i = 0; i < 8; ++i) {
            int id = tid + i * 256;
            int row = id >> 4, q4 = id & 15;
            int n_src;
            if (!POOL) n_src = nb * 128 + row;
            else {
                int v = row >> 6, m = nb * 64 + (row & 63);
                int p = m >> LGS, s = m & ((1 << LGS) - 1);
                n_src = ((2 * p + v) << LGS) + s;
            }
            const uint4 g = *(const uint4*)&xb[(size_t)n_src * 256 + c0u + q4 * 4];
            unsigned h01 = (g.x >> 16)     | (g.y & 0xFFFF0000u);
            unsigned h23 = (g.z >> 16)     | (g.w & 0xFFFF0000u);
            unsigned l01 = (g.x & 0xFFFFu) | (g.y << 16);
            unsigned l23 = (g.z & 0xFFFFu) | (g.w << 16);
            int byt = row * 128 + (((q4 >> 1) ^ (row & 7)) << 4) + ((q4 & 1) << 3);
            *(uint2*)((char*)Bh + byt) = make_uint2(h01, h23);
            *(uint2*)((char*)Bl + byt) = make_uint2(l01, l23);
        }
        __syncthreads();
        #pragma unroll
        for (int ks = 0; ks < 4; ++ks) {
            short8v ah[MF], al[MF];
            #pragma unroll
            for (int m = 0; m < MF; ++m) {
                int mfG = gy * 4 + (POOL ? ((wv >> 1) * 2 + m) : m);
                const unsigned int* ap =
                    wf + (size_t)((mfG * 16 + ko * 4 + ks) * 2) * 256 + lane * 4;
                ah[m] = *(const short8v*)ap;
                al[m] = *(const short8v*)(ap + 256);
            }
            #pragma unroll
            for (int v = 0; v < NV; ++v) {
                int row = POOL ? (v * 64 + (wv & 1) * 32 + (lane & 31))
                               : (wv * 32 + (lane & 31));
                int byt = row * 128 + (((ks * 2 + (lane >> 5)) ^ (row & 7)) << 4);
                short8v bh = *(const short8v*)((char*)Bh + byt);
                short8v bl = *(const short8v*)((char*)Bl + byt);
                #pragma unroll
                for (int m = 0; m < MF; ++m) {
                    acc[m][v] = __builtin_amdgcn_mfma_f32_32x32x16_bf16(ah[m], bh, acc[m][v], 0, 0, 0);
                    acc[m][v] = __builtin_amdgcn_mfma_f32_32x32x16_bf16(ah[m], bl, acc[m][v], 0, 0, 0);
                    acc[m][v] = __builtin_amdgcn_mfma_f32_32x32x16_bf16(al[m], bh, acc[m][v], 0, 0, 0);
                }
            }
        }
        __syncthreads();
    }

    float* ob = out + (size_t)b * obs;
    const int colbase = POOL ? (nb * 64 + (wv & 1) * 32 + (lane & 31))
                             : (nb * 128 + wv * 32 + (lane & 31));
    #pragma unroll
    for (int m = 0; m < MF; ++m) {
        int mfG = gy * 4 + (POOL ? ((wv >> 1) * 2 + m) : m);
        #pragma unroll
        for (int r = 0; r < 16; ++r) {
            int o = mfG * 32 + (r & 3) + 8 * (r >> 2) + 4 * (lane >> 5);
            float val = POOL ? fmaxf(acc[m][0][r], acc[m][1][r]) : acc[m][0][r];
            ob[(size_t)o * NS + colbase] = val + bias[o];
        }
    }
}

// ---------------------------------------------------------------- logits
template<int A, int AH, int PP, int G, int KS, int M>
__global__ __launch_bounds__(256) void logits_kernel(
    const float* __restrict__ qb, const float* __restrict__ kb,
    float* __restrict__ Lpart)
{
    const int tid = threadIdx.x;
    const int jl = tid & 63, pg = tid >> 6;
    const int p0 = pg * PP;
    const int b = blockIdx.z, a0 = blockIdx.y * G, kc = blockIdx.x;
    constexpr int CH = M / KS;
    const float* q = qb + (size_t)b * 8388608 + (size_t)a0 * M + (size_t)kc * CH;
    const float* k = kb + (size_t)b * 4194304;

    float acc[G][PP];
    #pragma unroll
    for (int g = 0; g < G; ++g)
        #pragma unroll
        for (int pp = 0; pp < PP; ++pp) acc[g][pp] = 0.f;

    for (int it = 0; it < CH / 64; ++it) {
        const int jo = jl + it * 64;
        const int j  = kc * CH + jo;
        float qv[G];
        #pragma unroll
        for (int g = 0; g < G; ++g) qv[g] = q[g * M + jo];
        float kv[PP];
        if (PP == 8) {
            float4 k0 = *(const float4*)&k[(size_t)j * AH + p0];
            float4 k1 = *(const float4*)&k[(size_t)j * AH + p0 + 4];
            kv[0]=k0.x; kv[1]=k0.y; kv[2]=k0.z; kv[3]=k0.w;
            kv[4]=k1.x; kv[5]=k1.y; kv[6]=k1.z; kv[7]=k1.w;
        } else {
            float2 k0 = *(const float2*)&k[(size_t)j * AH + p0];
            kv[0]=k0.x; if (PP > 1) kv[1]=k0.y;
        }
        #pragma unroll
        for (int g = 0; g < G; ++g)
            #pragma unroll
            for (int pp = 0; pp < PP; ++pp) acc[g][pp] += qv[g] * kv[pp];
    }

    #pragma unroll
    for (int g = 0; g < G; ++g)
        #pragma unroll
        for (int pp = 0; pp < PP; ++pp) {
            float v = acc[g][pp];
            #pragma unroll
            for (int off = 32; off; off >>= 1) v += __shfl_down(v, off, 64);
            if (jl == 0)
                Lpart[(size_t)(((b * A + a0 + g) * AH) + p0 + pp) * KS + kc] = v;
        }
}

// ---------------------------------------------------------------- softmax
__global__ __launch_bounds__(64) void softmax_kernel(
    const float* __restrict__ Lpart, float* __restrict__ attn,
    int AH, int KS)
{
    const int row = blockIdx.x;
    const int p = threadIdx.x;
    float s = 0.f;
    if (p < AH) {
        const size_t base = (size_t)(row * AH + p) * KS;
        for (int kc = 0; kc < KS; ++kc) s += Lpart[base + kc];
    }
    float m = (p < AH) ? s : -3.4e38f;
    #pragma unroll
    for (int off = 32; off; off >>= 1) m = fmaxf(m, __shfl_xor(m, off, 64));
    float e = (p < AH) ? __expf(s - m) : 0.f;
    float t = e;
    #pragma unroll
    for (int off = 32; off; off >>= 1) t += __shfl_xor(t, off, 64);
    if (p < AH) attn[(size_t)row * AH + p] = e / t;
}

// ---------------------------------------------------------------- apply
// o[b,x,a] = sum_p V[x,p]*attn[a,p];  xdst = gamma*o(un-permuted) + xsrc.
// Register-tiled: thread owns 4 rows x 4 a, float4 (b128) LDS reads.
// vls XOR-swizzled (chunk ^= (r>>2)&7, both sides) -> <=2-way banks.
// attnA staged [a][AH+4] (pad 36 -> broadcast 2-way max).
// cell0 (AH=8): V read direct from global (contiguous f4, L1-serviced).
// In-place safe: each elem read+written by the same thread (f4 read first).
template<int CELL>
__global__ __launch_bounds__(256) void apply_kernel(
    const float* __restrict__ vbuf, const float* __restrict__ attn,
    const float* __restrict__ xsrc, float* __restrict__ xdst,
    const float* __restrict__ gp, int gidx)
{
    constexpr int A  = (CELL == 0) ? 16 : 64;
    constexpr int AH = A / 2;            // 8 / 32
    constexpr int PADA = AH + 4;         // attnA row stride (12 / 36)
    constexpr int ITERS = (CELL == 1) ? 4 : 2;

    __shared__ float attnA[A * PADA];
    __shared__ float vls[(CELL == 0) ? 4 : 64 * 32];   // 8KB swizzled (1/2)

    const int tid = threadIdx.x;
    const int b = blockIdx.z, c = blockIdx.y;

    // stage attnA [a][p] padded (attn buffer is a-major: [b*A+a][p])
    for (int idx = tid; idx < A * AH / 4; idx += 256) {
        int a = idx / (AH / 4), q = idx % (AH / 4);
        *(float4*)&attnA[a * PADA + q * 4] =
            *(const float4*)&attn[(size_t)b * A * AH + a * AH + q * 4];
    }

    const float g = gp[gidx];
    const float* xs = xsrc + (size_t)b * XBS + (size_t)c * 65536;
    float*       xd = xdst + (size_t)b * XBS + (size_t)c * 65536;
    const float* vb = vbuf + (size_t)b * 8388608;

    if (CELL == 0) {
        __syncthreads();
        const int i0 = blockIdx.x * 8;
        const int r0 = (tid & 63) * 4;          // rows = i_l*64 + j (4 same-i j's)
        const int il = r0 >> 6, j0 = r0 & 63;
        const int a0 = (tid >> 6) * 4;
        float4 aa[2][4];
        #pragma unroll
        for (int ch = 0; ch < 2; ++ch)
            #pragma unroll
            for (int at = 0; at < 4; ++at)
                aa[ch][at] = *(const float4*)&attnA[(a0 + at) * PADA + ch * 4];
        for (int ig = 0; ig < 2; ++ig) {
            const int i = i0 + ig * 4 + il;
            const float* vrow = vb + ((size_t)(c * 64 + i) * 64 + j0) * 8;
            float acc[4][4];
            #pragma unroll
            for (int rt = 0; rt < 4; ++rt)
                #pragma unroll
                for (int at = 0; at < 4; ++at) acc[rt][at] = 0.f;
            #pragma unroll
            for (int ch = 0; ch < 2; ++ch)
                #pragma unroll
                for (int rt = 0; rt < 4; ++rt) {
                    float4 vv = *(const float4*)&vrow[rt * 8 + ch * 4];
                    #pragma unroll
                    for (int at = 0; at < 4; ++at)
                        acc[rt][at] += vv.x * aa[ch][at].x + vv.y * aa[ch][at].y
                                     + vv.z * aa[ch][at].z + vv.w * aa[ch][at].w;
                }
            #pragma unroll
            for (int at = 0; at < 4; ++at) {
                int a = a0 + at;
                size_t xi = (size_t)a * 4096 + i * 64 + j0;
                float4 sv = *(const float4*)&xs[xi];
                *(float4*)&xd[xi] = make_float4(
                    g * acc[0][at] + sv.x, g * acc[1][at] + sv.y,
                    g * acc[2][at] + sv.z, g * acc[3][at] + sv.w);
            }
        }
    } else {
        const int k = tid & 15, r0 = k * 4;     // row-quad (j / i*16+j)
        const int a0 = (tid >> 4) * 4;
        for (int itn = 0; itn < ITERS; ++itn) {
            const int ib = (CELL == 1) ? (blockIdx.x * 4 + itn)
                                       : ((blockIdx.x * 2 + itn) * 4);
            __syncthreads();   // prior-iter LDS reads done (+attnA at itn=0)
            {  // stage 64 rows x 32 p, XOR-swizzled
                const int rowbase = c * 1024 + ib * ((CELL == 1) ? 64 : 16);
                const float* src = vb + (size_t)rowbase * 32;
                int rr = tid >> 3, cc = tid & 7;
                #pragma unroll
                for (int u = 0; u < 2; ++u) {
                    int r = rr + u * 32;
                    int slot = cc ^ ((r >> 2) & 7);
                    *(float4*)&vls[r * 32 + slot * 4] =
                        *(const float4*)&src[r * 32 + cc * 4];
                }
            }
            __syncthreads();
            float acc[4][4];
            #pragma unroll
            for (int rt = 0; rt < 4; ++rt)
                #pragma unroll
                for (int at = 0; at < 4; ++at) acc[rt][at] = 0.f;
            #pragma unroll
            for (int ch = 0; ch < 8; ++ch) {
                const int slot = (ch ^ (k & 7)) * 4;   // (r0>>2)&7 == k&7
                float4 aa[4];
                #pragma unroll
                for (int at = 0; at < 4; ++at)
                    aa[at] = *(const float4*)&attnA[(a0 + at) * PADA + ch * 4];
                #pragma unroll
                for (int rt = 0; rt < 4; ++rt) {
                    float4 vv = *(const float4*)&vls[(r0 + rt) * 32 + slot];
                    #pragma unroll
                    for (int at = 0; at < 4; ++at)
                        acc[rt][at] += vv.x * aa[at].x + vv.y * aa[at].y
                                     + vv.z * aa[at].z + vv.w * aa[at].w;
                }
            }
            if (CELL == 1) {
                const int i = ib, j0 = r0;
                #pragma unroll
                for (int at = 0; at < 4; ++at) {
                    int a = a0 + at;
                    size_t xi = (size_t)i * 4096 + a * 64 + j0;
                    float4 sv = *(const float4*)&xs[xi];
                    *(float4*)&xd[xi] = make_float4(
                        g * acc[0][at] + sv.x, g * acc[1][at] + sv.y,
                        g * acc[2][at] + sv.z, g * acc[3][at] + sv.w);
                }
            } else {
                #pragma unroll
                for (int rt = 0; rt < 4; ++rt) {
                    int r = r0 + rt;
                    int i = ib + (r >> 4), j = r & 15;
                    size_t xi = (size_t)i * 1024 + j * 64 + a0;
                    float4 sv = *(const float4*)&xs[xi];
                    *(float4*)&xd[xi] = make_float4(
                        g * acc[rt][0] + sv.x, g * acc[rt][1] + sv.y,
                        g * acc[rt][2] + sv.z, g * acc[rt][3] + sv.w);
                }
            }
        }
    }
}

// ---------------------------------------------------------------- launch
extern "C" void kernel_launch(void* const* d_in, const int* in_sizes, int n_in,
                              void* d_out, int out_size, void* d_ws, size_t ws_size,
                              hipStream_t stream)
{
    const float* x  = (const float*)d_in[0];
    const float* Wq = (const float*)d_in[1];
    const float* bq = (const float*)d_in[2];
    const float* Wk = (const float*)d_in[3];
    const float* bk = (const float*)d_in[4];
    const float* Wv = (const float*)d_in[5];
    const float* bv = (const float*)d_in[6];
    const float* gm = (const float*)d_in[7];
    float* out = (float*)d_out;

    float* ws   = (float*)d_ws;
    float* qbuf = ws;                      // 16777216 f
    float* kbuf = qbuf + 16777216;         //  8388608 f
    float* vbuf = kbuf + 8388608;          // 16777216 f
    float* Lp   = vbuf + 16777216;         //    65536 f
    float* attn = Lp + 65536;              //     4096 f
    unsigned int* wfb = (unsigned int*)(attn + 4096);   // 3*131072 u32 (1.5MiB)
    unsigned int* xTp = wfb + 3 * 131072;               // 33554432 u32 (128MiB)

    dim3 B256(256), B64(64);

    // weight prep (frag-ordered bf16 hi/lo) — data-independent, once up front
    for (int c = 0; c < 3; ++c) {
        unsigned int* wfc = wfb + c * 131072;
        prep_w<<<dim3(16,4,2),B64,0,stream>>>(Wq + c*32768, wfc);
        prep_w<<<dim3(16,4,2),B64,0,stream>>>(Wk + c*32768, wfc + 32768);
        prep_w<<<dim3(16,8,2),B64,0,stream>>>(Wv + c*65536, wfc + 65536);
    }

    // ---- cell 0: 'T' ----
    xsplit_kernel<0><<<dim3(1024,4,2),B256,0,stream>>>(x, xTp);
    mconv<false,12><<<dim3(512,1,2),B256,0,stream>>>(xTp, wfb,          bq, qbuf, 8388608);
    mconv<true ,12><<<dim3(512,1,2),B256,0,stream>>>(xTp, wfb + 32768,  bk, kbuf, 4194304);
    mconv<true ,12><<<dim3(512,2,2),B256,0,stream>>>(xTp, wfb + 65536,  bv, vbuf, 8388608);
    logits_kernel<16,8,2,8,64,524288><<<dim3(64,2,2),B256,0,stream>>>(qbuf, kbuf, Lp);
    softmax_kernel<<<dim3(32),B64,0,stream>>>(Lp, attn, 8, 64);
    apply_kernel<0><<<dim3(8,256,2),B256,0,stream>>>(vbuf, attn, x, out, gm, 0);

    // ---- cell 1: 'W' ----
    unsigned int* wf1 = wfb + 131072;
    xsplit_kernel<1><<<dim3(1024,4,2),B256,0,stream>>>(out, xTp);
    mconv<false,10><<<dim3(512,1,2),B256,0,stream>>>(xTp, wf1,          bq+128, qbuf, 8388608);
    mconv<true ,10><<<dim3(512,1,2),B256,0,stream>>>(xTp, wf1 + 32768,  bk+128, kbuf, 4194304);
    mconv<true ,10><<<dim3(512,2,2),B256,0,stream>>>(xTp, wf1 + 65536,  bv+256, vbuf, 8388608);
    logits_kernel<64,32,8,8,16,131072><<<dim3(16,8,2),B256,0,stream>>>(qbuf, kbuf, Lp);
    softmax_kernel<<<dim3(128),B64,0,stream>>>(Lp, attn, 32, 16);
    apply_kernel<1><<<dim3(4,256,2),B256,0,stream>>>(vbuf, attn, out, out, gm, 1);

    // ---- cell 2: 'H' ----
    unsigned int* wf2 = wfb + 262144;
    xsplit_kernel<2><<<dim3(1024,4,2),B256,0,stream>>>(out, xTp);
    mconv<false,10><<<dim3(512,1,2),B256,0,stream>>>(xTp, wf2,          bq+256, qbuf, 8388608);
    mconv<true ,10><<<dim3(512,1,2),B256,0,stream>>>(xTp, wf2 + 32768,  bk+256, kbuf, 4194304);
    mconv<true ,10><<<dim3(512,2,2),B256,0,stream>>>(xTp, wf2 + 65536,  bv+512, vbuf, 8388608);
    logits_kernel<64,32,8,8,16,131072><<<dim3(16,8,2),B256,0,stream>>>(qbuf, kbuf, Lp);
    softmax_kernel<<<dim3(128),B64,0,stream>>>(Lp, attn, 32, 16);
    apply_kernel<2><<<dim3(8,256,2),B256,0,stream>>>(vbuf, attn, out, out, gm, 2);
}